// Round 5
// baseline (305.718 us; speedup 1.0000x reference)
//
#include <hip/hip_runtime.h>
#include <hip/hip_bf16.h>

// Problem dims
#define NTOK 8192       // B*T
#define NASN 16384      // NTOK * K(=2)
#define C_ 512
#define H_ 2048
#define E_ 8
#define NCH 128         // token chunks for atomic spreading
#define CHTOK 64        // tokens per chunk
#define MAXT 136        // max total 128-row m-tiles

typedef __bf16 bf16x8 __attribute__((ext_vector_type(8)));
typedef float f32x4 __attribute__((ext_vector_type(4)));

// Workspace layout (bytes). Total ~109.4 MB.
#define WS_COUNTS 0                              // NCH*8*4 = 4096
#define WS_BASE   4096                           // NCH*8*4 = 4096
#define WS_OFFS   8192                           // 9*4 -> pad 256
#define WS_T1S    8448                           // 9*4 -> pad 256
#define WS_INFO   8704                           // NTOK*16
#define WS_TOKL   (WS_INFO + NTOK*16)            // NASN*4
#define WS_SLOTS  (WS_TOKL + NASN*4)             // NTOK*8 (int2)
#define WS_XBF    (WS_SLOTS + NTOK*8)            // NTOK*C_*2 bf16 token-ordered x
#define WS_W1B    (WS_XBF + (size_t)NTOK*C_*2)   // E*H*C bf16, [e][h][c]
#define WS_W2B    (WS_W1B + (size_t)E_*H_*C_*2)  // E*C*H bf16, [e][c][h]
#define WS_HS     (WS_W2B + (size_t)E_*H_*C_*2)  // NASN*H bf16 hidden acts
// Ys (bf16, NASN*C_*2 = 16.78 MB) aliases Xbf+W1b (25.2 MB, dead by k_gemm2).
#define WS_YS     WS_XBF

__device__ __forceinline__ unsigned int f2bf(float f) {
  __hip_bfloat16 h = __float2bfloat16(f);
  return (unsigned int)*(unsigned short*)&h;
}
__device__ __forceinline__ float bf2f(unsigned int u) {
  return __int_as_float((u & 0xffffu) << 16);
}

// async global->LDS, 16B per lane; LDS dest = wave-uniform base + lane*16
__device__ __forceinline__ void g2l16(const unsigned short* g, unsigned short* l) {
  __builtin_amdgcn_global_load_lds(
      (const __attribute__((address_space(1))) unsigned int*)g,
      (__attribute__((address_space(3))) unsigned int*)l, 16, 0, 0);
}

// ---------------- router: one wave per token, fp32; also emits bf16 Xbf ----------------
__global__ __launch_bounds__(256) void k_router(
    const float* __restrict__ x, const float* __restrict__ Wr,
    const float* __restrict__ br, float* __restrict__ out_logits,
    float* __restrict__ out_idx, int4* __restrict__ info,
    int* __restrict__ counts, unsigned short* __restrict__ Xbf)
{
  int t = blockIdx.x * 4 + (threadIdx.x >> 6);
  int lane = threadIdx.x & 63;
  const float4* xr = (const float4*)(x + (size_t)t * C_);
  float4 x0 = xr[lane*2], x1 = xr[lane*2+1];
  // bf16 copy of the row (token order) for gemm1 staging
  uint4 pk;
  pk.x = f2bf(x0.x) | (f2bf(x0.y) << 16);
  pk.y = f2bf(x0.z) | (f2bf(x0.w) << 16);
  pk.z = f2bf(x1.x) | (f2bf(x1.y) << 16);
  pk.w = f2bf(x1.z) | (f2bf(x1.w) << 16);
  *(uint4*)(Xbf + (size_t)t * C_ + lane*8) = pk;

  float xs[8] = {x0.x,x0.y,x0.z,x0.w,x1.x,x1.y,x1.z,x1.w};
  float acc[8] = {0,0,0,0,0,0,0,0};
  #pragma unroll
  for (int j = 0; j < 8; j++) {
    const float4* w = (const float4*)(Wr + (size_t)(lane*8+j) * E_);
    float4 w0 = w[0], w1 = w[1];
    float we[8] = {w0.x,w0.y,w0.z,w0.w,w1.x,w1.y,w1.z,w1.w};
    #pragma unroll
    for (int e = 0; e < 8; e++) acc[e] += xs[j] * we[e];
  }
  #pragma unroll
  for (int off = 1; off < 64; off <<= 1) {
    #pragma unroll
    for (int e = 0; e < 8; e++) acc[e] += __shfl_xor(acc[e], off, 64);
  }
  #pragma unroll
  for (int e = 0; e < 8; e++) acc[e] += br[e];
  if (lane == 0) {
    #pragma unroll
    for (int e = 0; e < 8; e++) out_logits[t*8 + e] = acc[e];
    int i0 = 0; float v0 = acc[0];
    #pragma unroll
    for (int e = 1; e < 8; e++) if (acc[e] > v0) { v0 = acc[e]; i0 = e; }
    int i1 = -1; float v1 = -1e30f;
    #pragma unroll
    for (int e = 0; e < 8; e++) if (e != i0 && acc[e] > v1) { v1 = acc[e]; i1 = e; }
    float d = expf(v1 - v0);
    float s1 = d / (1.0f + d);
    float s0 = 1.0f - s1;
    out_idx[t*2]     = (float)i0;
    out_idx[t*2 + 1] = (float)i1;
    info[t] = make_int4(i0, i1, __float_as_int(s0), __float_as_int(s1));
    int ch = t >> 6;
    atomicAdd(&counts[ch*8 + i0], 1);
    atomicAdd(&counts[ch*8 + i1], 1);
  }
}

// ---------------- prefix: per-chunk/per-expert slot bases ----------------
__global__ __launch_bounds__(256) void k_prefix(
    const int* __restrict__ counts, int* __restrict__ base,
    int* __restrict__ offs, int* __restrict__ t1s)
{
  __shared__ int lc[NCH*8];
  __shared__ int tot[8];
  __shared__ int off_s[9];
  int tid = threadIdx.x;
  for (int i = tid; i < NCH*8; i += 256) lc[i] = counts[i];
  __syncthreads();
  if (tid < 8) {
    int run = 0;
    for (int c = 0; c < NCH; c++) { int v = lc[c*8+tid]; lc[c*8+tid] = run; run += v; }
    tot[tid] = run;
  }
  __syncthreads();
  if (tid == 0) {
    int o = 0, t = 0;
    off_s[0] = 0; offs[0] = 0; t1s[0] = 0;
    for (int e = 0; e < 8; e++) {
      o += tot[e];
      off_s[e+1] = o; offs[e+1] = o;
      t += (tot[e] + 127) >> 7;
      t1s[e+1] = t;
    }
  }
  __syncthreads();
  for (int i = tid; i < NCH*8; i += 256) base[i] = off_s[i & 7] + lc[i];
}

// ---------------- scatter: chunk-local LDS rank -> slots ----------------
__global__ __launch_bounds__(64) void k_scatter(
    const int4* __restrict__ info, const int* __restrict__ base,
    int* __restrict__ tokl, int2* __restrict__ slots2)
{
  __shared__ int cur[8];
  int c = blockIdx.x, tid = threadIdx.x;
  if (tid < 8) cur[tid] = base[c*8 + tid];
  __syncthreads();
  int t = c * CHTOK + tid;
  int4 nfo = info[t];
  int r0 = atomicAdd(&cur[nfo.x], 1);
  int r1 = atomicAdd(&cur[nfo.y], 1);
  tokl[r0] = t;
  tokl[r1] = t;
  slots2[t] = make_int2(r0, r1);
}

// ---------------- weight transpose fp32[R][S] -> bf16[S][R] ----------------
__global__ __launch_bounds__(256) void k_transpose(
    const float* __restrict__ in, unsigned short* __restrict__ outp, int R, int S)
{
  __shared__ float tile[32][33];
  size_t zo = (size_t)blockIdx.z * R * S;
  in += zo; outp += zo;
  int s0 = blockIdx.x * 32, r0 = blockIdx.y * 32;
  int tx = threadIdx.x, ty = threadIdx.y;
  #pragma unroll
  for (int i = 0; i < 4; i++)
    tile[ty + i*8][tx] = in[(size_t)(r0 + ty + i*8) * S + s0 + tx];
  __syncthreads();
  #pragma unroll
  for (int i = 0; i < 4; i++)
    outp[(size_t)(s0 + ty + i*8) * R + r0 + tx] = f2bf(tile[tx][ty + i*8]);
}

// ---------------- grouped GEMM layer 1: Hs = relu(Xrows @ W1 + b1) ----------------
// 128x128 tile, BK=64, global_load_lds staging (A gathered via tokl), XOR LDS.
// 1D grid, XCD swizzle: all 16 n-tiles of an m-tile share blockIdx%8.
__global__ __launch_bounds__(256) void k_gemm1(
    const unsigned short* __restrict__ Xbf, const int* __restrict__ tokl,
    const unsigned short* __restrict__ W1b,
    const float* __restrict__ b1, unsigned short* __restrict__ Hs,
    const int* __restrict__ offs, const int* __restrict__ t1s)
{
  __shared__ __align__(16) unsigned short AB[2*128*64];   // 32 KB
  unsigned short* Al = AB;
  unsigned short* Bl = AB + 128*64;
  int b = blockIdx.x;
  int mo = b >> 7, rr = b & 127;
  int n0 = (rr >> 3) * 128;
  int mt = mo*8 + (rr & 7);
  if (mt >= t1s[8]) return;
  int e = 0;
  #pragma unroll
  for (int i = 0; i < 7; i++) if (mt >= t1s[e+1]) e++;
  int row0 = offs[e] + (mt - t1s[e]) * 128;
  int rowEnd = offs[e+1];
  int tid = threadIdx.x, lane = tid & 63, w = tid >> 6;
  int wm = (w & 1) * 64, wn = (w >> 1) * 64;
  int quad = lane >> 4, l16 = lane & 15;
  const f32x4 zero = {0.f, 0.f, 0.f, 0.f};
  f32x4 acc[4][4];
  #pragma unroll
  for (int i = 0; i < 4; i++)
    #pragma unroll
    for (int j = 0; j < 4; j++) acc[i][j] = zero;
  const unsigned short* Bsrc = W1b + ((size_t)e * H_ + n0) * C_;

  const unsigned short* ga[4]; const unsigned short* gb[4];
  unsigned short* la[4]; unsigned short* lb[4];
  #pragma unroll
  for (int j = 0; j < 4; j++) {
    int L = (w*4 + j)*64 + lane;
    int row = L >> 3;
    int cc = (L & 7) ^ (row & 7);
    int gr = row0 + row; gr = gr < NASN-1 ? gr : NASN-1;
    int trow = tokl[gr];                     // gather via token index
    ga[j] = Xbf + (size_t)trow * C_ + cc*8;
    gb[j] = Bsrc + (size_t)row * C_ + cc*8;
    la[j] = Al + (w*4 + j)*512;
    lb[j] = Bl + (w*4 + j)*512;
  }
  int r7 = l16 & 7;

  for (int kk = 0; kk < C_; kk += 64) {
    #pragma unroll
    for (int j = 0; j < 4; j++) {
      g2l16(ga[j] + kk, la[j]);
      g2l16(gb[j] + kk, lb[j]);
    }
    __syncthreads();
    #pragma unroll
    for (int ks4 = 0; ks4 < 8; ks4 += 4) {
      int chunk = (ks4 + quad) ^ r7;
      bf16x8 af[4], bfr[4];
      #pragma unroll
      for (int i = 0; i < 4; i++)
        af[i] = *(const bf16x8*)&Al[(wm + i*16 + l16)*64 + chunk*8];
      #pragma unroll
      for (int j = 0; j < 4; j++)
        bfr[j] = *(const bf16x8*)&Bl[(wn + j*16 + l16)*64 + chunk*8];
      #pragma unroll
      for (int i = 0; i < 4; i++)
        #pragma unroll
        for (int j = 0; j < 4; j++)
          acc[i][j] = __builtin_amdgcn_mfma_f32_16x16x32_bf16(af[i], bfr[j], acc[i][j], 0, 0, 0);
    }
    __syncthreads();
  }

  // epilogue: per-wave LDS transpose -> coalesced 16B stores
  unsigned short* Lt = AB + w*4096;   // 64x64 bf16 per wave
  #pragma unroll
  for (int j = 0; j < 4; j++) {
    int n = n0 + wn + j*16 + l16;
    float bias = b1[e * H_ + n];
    #pragma unroll
    for (int i = 0; i < 4; i++)
      #pragma unroll
      for (int r = 0; r < 4; r++) {
        float v = acc[i][j][r] + bias;
        Lt[(i*16 + quad*4 + r)*64 + j*16 + l16] = (unsigned short)f2bf(v > 0.f ? v : 0.f);
      }
  }
  #pragma unroll
  for (int it = 0; it < 8; it++) {
    int rloc = it*8 + (lane >> 3);
    int m = row0 + wm + rloc;
    uint4 vv = *(uint4*)&Lt[rloc*64 + (lane & 7)*8];
    if (m < rowEnd)
      *(uint4*)(Hs + (size_t)m * H_ + n0 + wn + (lane & 7)*8) = vv;
  }
}

// ---------------- grouped GEMM layer 2: Ys(bf16) = Hs @ W2 + b2 ----------------
// 512 threads = 8 waves: wave w -> quadrant w>>1, K-half w&1 (intra-block
// split-K). LDS holds both 64-col K-panels (64 KB, single buffer). 16 iters.
// Cross-wave reduction via swizzled LDS exchange. 1D grid, XCD swizzle.
__global__ __launch_bounds__(512) void k_gemm2(
    const unsigned short* __restrict__ Hs, const unsigned short* __restrict__ W2b,
    const float* __restrict__ b2, unsigned short* __restrict__ Ys,
    const int* __restrict__ offs, const int* __restrict__ t1s)
{
  __shared__ __align__(16) unsigned short AB[2*2*128*64];   // 64 KB
  int b = blockIdx.x;
  int g = b >> 5, rr = b & 31;
  int n0 = (rr >> 3) * 128;
  int mt = g*8 + (rr & 7);
  if (mt >= t1s[8]) return;
  int e = 0;
  #pragma unroll
  for (int i = 0; i < 7; i++) if (mt >= t1s[e+1]) e++;
  int row0 = offs[e] + (mt - t1s[e]) * 128;
  int rowEnd = offs[e+1];
  int tid = threadIdx.x, lane = tid & 63, w = tid >> 6;
  int wq = w >> 1, kh = w & 1;
  int wm = (wq & 1) * 64, wn = (wq >> 1) * 64;
  int quad = lane >> 4, l16 = lane & 15;
  const f32x4 zero = {0.f, 0.f, 0.f, 0.f};
  f32x4 acc[4][4];
  #pragma unroll
  for (int i = 0; i < 4; i++)
    #pragma unroll
    for (int j = 0; j < 4; j++) acc[i][j] = zero;
  const unsigned short* Bsrc = W2b + ((size_t)e * C_ + n0) * H_;

  const unsigned short* ga[4]; const unsigned short* gb[4];
  unsigned short* la[4]; unsigned short* lb[4];
  #pragma unroll
  for (int j = 0; j < 4; j++) {
    int L = (wq*4 + j)*64 + lane;
    int row = L >> 3;
    int cc = (L & 7) ^ (row & 7);
    int gr = row0 + row; gr = gr < NASN-1 ? gr : NASN-1;
    ga[j] = Hs + (size_t)gr * H_ + kh*1024 + cc*8;
    gb[j] = Bsrc + (size_t)row * H_ + kh*1024 + cc*8;
    la[j] = AB + kh*16384 + (wq*4 + j)*512;
    lb[j] = AB + kh*16384 + 8192 + (wq*4 + j)*512;
  }
  int r7 = l16 & 7;
  const unsigned short* Ap = AB + kh*16384;
  const unsigned short* Bp = AB + kh*16384 + 8192;

  for (int kk = 0; kk < 1024; kk += 64) {
    #pragma unroll
    for (int j = 0; j < 4; j++) {
      g2l16(ga[j] + kk, la[j]);
      g2l16(gb[j] + kk, lb[j]);
    }
    __syncthreads();
    #pragma unroll
    for (int ks4 = 0; ks4 < 8; ks4 += 4) {
      int chunk = (ks4 + quad) ^ r7;
      bf16x8 af[4], bfr[4];
      #pragma unroll
      for (int i = 0; i < 4; i++)
        af[i] = *(const bf16x8*)&Ap[(wm + i*16 + l16)*64 + chunk*8];
      #pragma unroll
      for (int j = 0; j < 4; j++)
        bfr[j] = *(const bf16x8*)&Bp[(wn + j*16 + l16)*64 + chunk*8];
      #pragma unroll
      for (int i = 0; i < 4; i++)
        #pragma unroll
        for (int j = 0; j < 4; j++)
          acc[i][j] = __builtin_amdgcn_mfma_f32_16x16x32_bf16(af[i], bfr[j], acc[i][j], 0, 0, 0);
    }
    __syncthreads();
  }

  // cross-wave K-half reduction: kh=1 stores (swizzled 16B chunks), kh=0 adds.
  float* X = (float*)AB;                 // 16K fp32; region wq*4096 (16 KB each)
  if (kh == 1) {
    #pragma unroll
    for (int i = 0; i < 4; i++)
      #pragma unroll
      for (int j = 0; j < 4; j++) {
        int c = j*16 + l16;              // quadrant-local col
        int slot = (i*4 + quad) ^ (c & 15);
        *(f32x4*)&X[wq*4096 + c*64 + slot*4] = acc[i][j];
      }
  }
  __syncthreads();
  if (kh == 0) {
    #pragma unroll
    for (int j = 0; j < 4; j++) {
      int c = j*16 + l16;
      float bias = b2[e * C_ + n0 + wn + c];
      #pragma unroll
      for (int i = 0; i < 4; i++) {
        int slot = (i*4 + quad) ^ (c & 15);
        f32x4 p = *(const f32x4*)&X[wq*4096 + c*64 + slot*4];
        #pragma unroll
        for (int r = 0; r < 4; r++) acc[i][j][r] += p[r] + bias;
      }
    }
  }
  __syncthreads();
  if (kh == 0) {
    // transpose via private 8KB LDS region, then coalesced bf16 stores
    unsigned short* Lt = AB + wq*4096;
    #pragma unroll
    for (int j = 0; j < 4; j++)
      #pragma unroll
      for (int i = 0; i < 4; i++)
        #pragma unroll
        for (int r = 0; r < 4; r++)
          Lt[(i*16 + quad*4 + r)*64 + j*16 + l16] =
              (unsigned short)f2bf(acc[i][j][r]);
    #pragma unroll
    for (int it = 0; it < 8; it++) {
      int rloc = it*8 + (lane >> 3);
      int m = row0 + wm + rloc;
      uint4 vv = *(uint4*)&Lt[rloc*64 + (lane & 7)*8];
      if (m < rowEnd)
        *(uint4*)(Ys + (size_t)m * C_ + n0 + wn + (lane & 7)*8) = vv;
    }
  }
}

// ---------------- combine: out[t] = g0*Ys[s0] + g1*Ys[s1] (bf16 Ys) ----------------
__global__ __launch_bounds__(256) void k_combine(
    const unsigned short* __restrict__ Ys, const int4* __restrict__ info,
    const int2* __restrict__ slots2, float* __restrict__ outp)
{
  int t = blockIdx.x * 4 + (threadIdx.x >> 6);
  int lane = threadIdx.x & 63;
  int4 nfo = info[t];
  int2 ss = slots2[t];
  float g0 = __int_as_float(nfo.z), g1 = __int_as_float(nfo.w);
  uint4 a = *(const uint4*)(Ys + (size_t)ss.x * C_ + lane*8);
  uint4 bb = *(const uint4*)(Ys + (size_t)ss.y * C_ + lane*8);
  unsigned int au[4] = {a.x, a.y, a.z, a.w};
  unsigned int bu[4] = {bb.x, bb.y, bb.z, bb.w};
  float4 o0, o1;
  float* op = &o0.x;
  #pragma unroll
  for (int q = 0; q < 4; q++) {
    op[q*2 - (q>=2?0:0)] = 0; // placate nothing
  }
  float vals[8];
  #pragma unroll
  for (int q = 0; q < 4; q++) {
    vals[q*2]   = g0*bf2f(au[q])        + g1*bf2f(bu[q]);
    vals[q*2+1] = g0*bf2f(au[q] >> 16)  + g1*bf2f(bu[q] >> 16);
  }
  o0.x = vals[0]; o0.y = vals[1]; o0.z = vals[2]; o0.w = vals[3];
  o1.x = vals[4]; o1.y = vals[5]; o1.z = vals[6]; o1.w = vals[7];
  float4* o = (float4*)(outp + (size_t)t * C_ + lane*8);
  o[0] = o0;
  o[1] = o1;
}

extern "C" void kernel_launch(void* const* d_in, const int* in_sizes, int n_in,
                              void* d_out, int out_size, void* d_ws, size_t ws_size,
                              hipStream_t stream)
{
  const float* x  = (const float*)d_in[0];
  const float* Wr = (const float*)d_in[1];
  const float* br = (const float*)d_in[2];
  const float* W1 = (const float*)d_in[3];
  const float* b1 = (const float*)d_in[4];
  const float* W2 = (const float*)d_in[5];
  const float* b2 = (const float*)d_in[6];
  float* out = (float*)d_out;   // [logits 65536 | idx 16384 | out 4194304]
  char* ws = (char*)d_ws;

  int*  counts = (int*)(ws + WS_COUNTS);
  int*  base   = (int*)(ws + WS_BASE);
  int*  offs   = (int*)(ws + WS_OFFS);
  int*  t1s    = (int*)(ws + WS_T1S);
  int4* info   = (int4*)(ws + WS_INFO);
  int*  tokl   = (int*)(ws + WS_TOKL);
  int2* slots2 = (int2*)(ws + WS_SLOTS);
  unsigned short* Xbf = (unsigned short*)(ws + WS_XBF);
  unsigned short* W1b = (unsigned short*)(ws + WS_W1B);
  unsigned short* W2b = (unsigned short*)(ws + WS_W2B);
  unsigned short* Hs  = (unsigned short*)(ws + WS_HS);
  unsigned short* Ys  = (unsigned short*)(ws + WS_YS);  // aliases Xbf+W1b

  hipMemsetAsync(counts, 0, NCH*8*sizeof(int), stream);

  k_transpose<<<dim3(H_/32, C_/32, E_), dim3(32, 8), 0, stream>>>(W1, W1b, C_, H_);
  k_transpose<<<dim3(C_/32, H_/32, E_), dim3(32, 8), 0, stream>>>(W2, W2b, H_, C_);
  k_router<<<NTOK/4, 256, 0, stream>>>(x, Wr, br, out, out + 65536, info, counts, Xbf);
  k_prefix<<<1, 256, 0, stream>>>(counts, base, offs, t1s);
  k_scatter<<<NCH, 64, 0, stream>>>(info, base, tokl, slots2);
  k_gemm1<<<17*128, 256, 0, stream>>>(Xbf, tokl, W1b, b1, Hs, offs, t1s);
  k_gemm2<<<17*32, 512, 0, stream>>>(Hs, W2b, b2, Ys, offs, t1s);
  k_combine<<<NTOK/4, 256, 0, stream>>>(Ys, info, slots2, out + 81920);
}

// Round 6
// 279.612 us; speedup vs baseline: 1.0934x; 1.0934x over previous
//
#include <hip/hip_runtime.h>
#include <hip/hip_bf16.h>

// Problem dims
#define NTOK 8192       // B*T
#define NASN 16384      // NTOK * K(=2)
#define C_ 512
#define H_ 2048
#define E_ 8
#define NCH 128         // token chunks for atomic spreading
#define CHTOK 64        // tokens per chunk

typedef __bf16 bf16x8 __attribute__((ext_vector_type(8)));
typedef float f32x4 __attribute__((ext_vector_type(4)));

// Workspace layout (bytes). Total ~109.4 MB.
#define WS_COUNTS 0                              // NCH*8*4 = 4096
#define WS_BASE   4096                           // NCH*8*4 = 4096
#define WS_OFFS   8192                           // 9*4 -> pad 256
#define WS_T1S    8448                           // 9*4 -> pad 256
#define WS_INFO   8704                           // NTOK*16
#define WS_TOKL   (WS_INFO + NTOK*16)            // NASN*4
#define WS_SLOTS  (WS_TOKL + NASN*4)             // NTOK*8 (int2)
#define WS_XBF    (WS_SLOTS + NTOK*8)            // NTOK*C_*2 bf16 token-ordered x
#define WS_W1B    (WS_XBF + (size_t)NTOK*C_*2)   // E*H*C bf16, [e][h][c]
#define WS_W2B    (WS_W1B + (size_t)E_*H_*C_*2)  // E*C*H bf16, [e][c][h]
#define WS_HS     (WS_W2B + (size_t)E_*H_*C_*2)  // NASN*H bf16 hidden acts
// Ys (bf16, NASN*C_*2 = 16.78 MB) aliases Xbf+W1b (25.2 MB, dead by k_gemm2).
#define WS_YS     WS_XBF

__device__ __forceinline__ unsigned int f2bf(float f) {
  __hip_bfloat16 h = __float2bfloat16(f);
  return (unsigned int)*(unsigned short*)&h;
}
__device__ __forceinline__ float bf2f(unsigned int u) {
  return __int_as_float((u & 0xffffu) << 16);
}

// async global->LDS, 16B per lane; LDS dest = wave-uniform base + lane*16
__device__ __forceinline__ void g2l16(const unsigned short* g, unsigned short* l) {
  __builtin_amdgcn_global_load_lds(
      (const __attribute__((address_space(1))) unsigned int*)g,
      (__attribute__((address_space(3))) unsigned int*)l, 16, 0, 0);
}

// ---------------- router: one wave per token, fp32; also emits bf16 Xbf ----------------
__global__ __launch_bounds__(256) void k_router(
    const float* __restrict__ x, const float* __restrict__ Wr,
    const float* __restrict__ br, float* __restrict__ out_logits,
    float* __restrict__ out_idx, int4* __restrict__ info,
    int* __restrict__ counts, unsigned short* __restrict__ Xbf)
{
  int t = blockIdx.x * 4 + (threadIdx.x >> 6);
  int lane = threadIdx.x & 63;
  const float4* xr = (const float4*)(x + (size_t)t * C_);
  float4 x0 = xr[lane*2], x1 = xr[lane*2+1];
  uint4 pk;
  pk.x = f2bf(x0.x) | (f2bf(x0.y) << 16);
  pk.y = f2bf(x0.z) | (f2bf(x0.w) << 16);
  pk.z = f2bf(x1.x) | (f2bf(x1.y) << 16);
  pk.w = f2bf(x1.z) | (f2bf(x1.w) << 16);
  *(uint4*)(Xbf + (size_t)t * C_ + lane*8) = pk;

  float xs[8] = {x0.x,x0.y,x0.z,x0.w,x1.x,x1.y,x1.z,x1.w};
  float acc[8] = {0,0,0,0,0,0,0,0};
  #pragma unroll
  for (int j = 0; j < 8; j++) {
    const float4* w = (const float4*)(Wr + (size_t)(lane*8+j) * E_);
    float4 w0 = w[0], w1 = w[1];
    float we[8] = {w0.x,w0.y,w0.z,w0.w,w1.x,w1.y,w1.z,w1.w};
    #pragma unroll
    for (int e = 0; e < 8; e++) acc[e] += xs[j] * we[e];
  }
  #pragma unroll
  for (int off = 1; off < 64; off <<= 1) {
    #pragma unroll
    for (int e = 0; e < 8; e++) acc[e] += __shfl_xor(acc[e], off, 64);
  }
  #pragma unroll
  for (int e = 0; e < 8; e++) acc[e] += br[e];
  if (lane == 0) {
    #pragma unroll
    for (int e = 0; e < 8; e++) out_logits[t*8 + e] = acc[e];
    int i0 = 0; float v0 = acc[0];
    #pragma unroll
    for (int e = 1; e < 8; e++) if (acc[e] > v0) { v0 = acc[e]; i0 = e; }
    int i1 = -1; float v1 = -1e30f;
    #pragma unroll
    for (int e = 0; e < 8; e++) if (e != i0 && acc[e] > v1) { v1 = acc[e]; i1 = e; }
    float d = expf(v1 - v0);
    float s1 = d / (1.0f + d);
    float s0 = 1.0f - s1;
    out_idx[t*2]     = (float)i0;
    out_idx[t*2 + 1] = (float)i1;
    info[t] = make_int4(i0, i1, __float_as_int(s0), __float_as_int(s1));
    int ch = t >> 6;
    atomicAdd(&counts[ch*8 + i0], 1);
    atomicAdd(&counts[ch*8 + i1], 1);
  }
}

// ---------------- prefix: per-chunk/per-expert slot bases ----------------
__global__ __launch_bounds__(256) void k_prefix(
    const int* __restrict__ counts, int* __restrict__ base,
    int* __restrict__ offs, int* __restrict__ t1s)
{
  __shared__ int lc[NCH*8];
  __shared__ int tot[8];
  __shared__ int off_s[9];
  int tid = threadIdx.x;
  for (int i = tid; i < NCH*8; i += 256) lc[i] = counts[i];
  __syncthreads();
  if (tid < 8) {
    int run = 0;
    for (int c = 0; c < NCH; c++) { int v = lc[c*8+tid]; lc[c*8+tid] = run; run += v; }
    tot[tid] = run;
  }
  __syncthreads();
  if (tid == 0) {
    int o = 0, t = 0;
    off_s[0] = 0; offs[0] = 0; t1s[0] = 0;
    for (int e = 0; e < 8; e++) {
      o += tot[e];
      off_s[e+1] = o; offs[e+1] = o;
      t += (tot[e] + 127) >> 7;
      t1s[e+1] = t;
    }
  }
  __syncthreads();
  for (int i = tid; i < NCH*8; i += 256) base[i] = off_s[i & 7] + lc[i];
}

// ---------------- scatter: chunk-local LDS rank -> slots ----------------
__global__ __launch_bounds__(64) void k_scatter(
    const int4* __restrict__ info, const int* __restrict__ base,
    int* __restrict__ tokl, int2* __restrict__ slots2)
{
  __shared__ int cur[8];
  int c = blockIdx.x, tid = threadIdx.x;
  if (tid < 8) cur[tid] = base[c*8 + tid];
  __syncthreads();
  int t = c * CHTOK + tid;
  int4 nfo = info[t];
  int r0 = atomicAdd(&cur[nfo.x], 1);
  int r1 = atomicAdd(&cur[nfo.y], 1);
  tokl[r0] = t;
  tokl[r1] = t;
  slots2[t] = make_int2(r0, r1);
}

// ---------------- weight transpose fp32[R][S] -> bf16[S][R] ----------------
// 128(R) x 32(S) tile; vectorized 8B output stores.
__global__ __launch_bounds__(256) void k_transpose(
    const float* __restrict__ in, unsigned short* __restrict__ outp, int R, int S)
{
  __shared__ float tile[128][33];
  size_t zo = (size_t)blockIdx.z * R * S;
  in += zo; outp += zo;
  int r0 = blockIdx.y * 128, s0 = blockIdx.x * 32;
  int t = threadIdx.x;
  #pragma unroll
  for (int i = 0; i < 16; i++) {
    int lin = i*256 + t;
    int rr = lin >> 5, ss = lin & 31;
    tile[rr][ss] = in[(size_t)(r0 + rr) * S + s0 + ss];
  }
  __syncthreads();
  #pragma unroll
  for (int i = 0; i < 4; i++) {
    int lin = i*256 + t;
    int ss = lin >> 5, rq = lin & 31;
    ushort4 v;
    v.x = (unsigned short)f2bf(tile[rq*4+0][ss]);
    v.y = (unsigned short)f2bf(tile[rq*4+1][ss]);
    v.z = (unsigned short)f2bf(tile[rq*4+2][ss]);
    v.w = (unsigned short)f2bf(tile[rq*4+3][ss]);
    *(ushort4*)(outp + (size_t)(s0 + ss) * R + r0 + rq*4) = v;
  }
}

// ---------------- grouped GEMM layer 1: Hs = relu(Xrows @ W1 + b1) ----------------
// 128x128 tile, BK=32, 32KB LDS double-buffer (5 blocks/CU) + vmcnt(4)
// prefetch pipeline. A gathered via tokl. 1D grid, XCD swizzle.
__global__ __launch_bounds__(256) void k_gemm1(
    const unsigned short* __restrict__ Xbf, const int* __restrict__ tokl,
    const unsigned short* __restrict__ W1b,
    const float* __restrict__ b1, unsigned short* __restrict__ Hs,
    const int* __restrict__ offs, const int* __restrict__ t1s)
{
  __shared__ __align__(16) unsigned short AB[2*8192];   // 32 KB: 2 x (A 8KB + B 8KB)
  int b = blockIdx.x;
  int mo = b >> 7, rr = b & 127;
  int n0 = (rr >> 3) * 128;
  int mt = mo*8 + (rr & 7);
  if (mt >= t1s[8]) return;
  int e = 0;
  #pragma unroll
  for (int i = 0; i < 7; i++) if (mt >= t1s[e+1]) e++;
  int row0 = offs[e] + (mt - t1s[e]) * 128;
  int rowEnd = offs[e+1];
  int tid = threadIdx.x, lane = tid & 63, w = tid >> 6;
  int wm = (w & 1) * 64, wn = (w >> 1) * 64;
  int quad = lane >> 4, l16 = lane & 15;
  const f32x4 zero = {0.f, 0.f, 0.f, 0.f};
  f32x4 acc[4][4];
  #pragma unroll
  for (int i = 0; i < 4; i++)
    #pragma unroll
    for (int j = 0; j < 4; j++) acc[i][j] = zero;
  const unsigned short* Bsrc = W1b + ((size_t)e * H_ + n0) * C_;

  // staging: per wave 2 A-instr + 2 B-instr per iter. LDS 16B-chunk L covers
  // row L>>2, slot L&3 holding global chunk (L&3)^(row&3) (XOR swizzle).
  const unsigned short* ga[2]; const unsigned short* gb[2];
  int lao[2], lbo[2];
  #pragma unroll
  for (int j = 0; j < 2; j++) {
    int L = (w*2 + j)*64 + lane;
    int row = L >> 2;
    int gc = (L & 3) ^ (row & 3);
    int gr = row0 + row; gr = gr < NASN-1 ? gr : NASN-1;
    int trow = tokl[gr];
    ga[j] = Xbf + (size_t)trow * C_ + gc*8;
    gb[j] = Bsrc + (size_t)row * C_ + gc*8;
    lao[j] = (w*2 + j)*512;
    lbo[j] = 4096 + (w*2 + j)*512;
  }
  int r3 = l16 & 3;
  const int KI = C_ / 32;   // 16

  #pragma unroll
  for (int j = 0; j < 2; j++) { g2l16(ga[j], AB + lao[j]); g2l16(gb[j], AB + lbo[j]); }

  for (int ki = 0; ki < KI; ki++) {
    int p = ki & 1;
    if (ki + 1 < KI) {
      int off = (ki + 1) * 32;
      unsigned short* nb = AB + (p ^ 1) * 8192;
      #pragma unroll
      for (int j = 0; j < 2; j++) {
        g2l16(ga[j] + off, nb + lao[j]);
        g2l16(gb[j] + off, nb + lbo[j]);
      }
      asm volatile("s_waitcnt vmcnt(4)" ::: "memory");
    } else {
      asm volatile("s_waitcnt vmcnt(0)" ::: "memory");
    }
    asm volatile("s_barrier" ::: "memory");

    const unsigned short* Ap = AB + p*8192;
    const unsigned short* Bp = Ap + 4096;
    int sl = (quad ^ r3) * 8;
    bf16x8 af[4], bfr[4];
    #pragma unroll
    for (int i = 0; i < 4; i++)
      af[i] = *(const bf16x8*)&Ap[(wm + i*16 + l16)*32 + sl];
    #pragma unroll
    for (int j = 0; j < 4; j++)
      bfr[j] = *(const bf16x8*)&Bp[(wn + j*16 + l16)*32 + sl];
    #pragma unroll
    for (int i = 0; i < 4; i++)
      #pragma unroll
      for (int j = 0; j < 4; j++)
        acc[i][j] = __builtin_amdgcn_mfma_f32_16x16x32_bf16(af[i], bfr[j], acc[i][j], 0, 0, 0);

    asm volatile("s_waitcnt lgkmcnt(0)" ::: "memory");
    asm volatile("s_barrier" ::: "memory");
  }

  // epilogue: per-wave LDS transpose -> coalesced 16B stores
  unsigned short* Lt = AB + w*4096;   // 64x64 bf16 per wave (8 KB)
  #pragma unroll
  for (int j = 0; j < 4; j++) {
    int n = n0 + wn + j*16 + l16;
    float bias = b1[e * H_ + n];
    #pragma unroll
    for (int i = 0; i < 4; i++)
      #pragma unroll
      for (int r = 0; r < 4; r++) {
        float v = acc[i][j][r] + bias;
        Lt[(i*16 + quad*4 + r)*64 + j*16 + l16] = (unsigned short)f2bf(v > 0.f ? v : 0.f);
      }
  }
  #pragma unroll
  for (int it = 0; it < 8; it++) {
    int rloc = it*8 + (lane >> 3);
    int m = row0 + wm + rloc;
    uint4 vv = *(uint4*)&Lt[rloc*64 + (lane & 7)*8];
    if (m < rowEnd)
      *(uint4*)(Hs + (size_t)m * H_ + n0 + wn + (lane & 7)*8) = vv;
  }
}

// ---------------- grouped GEMM layer 2: Ys(bf16) = Hs @ W2 + b2 ----------------
// Same BK=32 dbuf pipeline; K=2048 (64 iters). 1D grid, XCD swizzle.
__global__ __launch_bounds__(256) void k_gemm2(
    const unsigned short* __restrict__ Hs, const unsigned short* __restrict__ W2b,
    const float* __restrict__ b2, unsigned short* __restrict__ Ys,
    const int* __restrict__ offs, const int* __restrict__ t1s)
{
  __shared__ __align__(16) unsigned short AB[2*8192];   // 32 KB
  int b = blockIdx.x;
  int g = b >> 5, rr = b & 31;
  int n0 = (rr >> 3) * 128;
  int mt = g*8 + (rr & 7);
  if (mt >= t1s[8]) return;
  int e = 0;
  #pragma unroll
  for (int i = 0; i < 7; i++) if (mt >= t1s[e+1]) e++;
  int row0 = offs[e] + (mt - t1s[e]) * 128;
  int rowEnd = offs[e+1];
  int tid = threadIdx.x, lane = tid & 63, w = tid >> 6;
  int wm = (w & 1) * 64, wn = (w >> 1) * 64;
  int quad = lane >> 4, l16 = lane & 15;
  const f32x4 zero = {0.f, 0.f, 0.f, 0.f};
  f32x4 acc[4][4];
  #pragma unroll
  for (int i = 0; i < 4; i++)
    #pragma unroll
    for (int j = 0; j < 4; j++) acc[i][j] = zero;
  const unsigned short* Bsrc = W2b + ((size_t)e * C_ + n0) * H_;

  const unsigned short* ga[2]; const unsigned short* gb[2];
  int lao[2], lbo[2];
  #pragma unroll
  for (int j = 0; j < 2; j++) {
    int L = (w*2 + j)*64 + lane;
    int row = L >> 2;
    int gc = (L & 3) ^ (row & 3);
    int gr = row0 + row; gr = gr < NASN-1 ? gr : NASN-1;
    ga[j] = Hs + (size_t)gr * H_ + gc*8;
    gb[j] = Bsrc + (size_t)row * H_ + gc*8;
    lao[j] = (w*2 + j)*512;
    lbo[j] = 4096 + (w*2 + j)*512;
  }
  int r3 = l16 & 3;
  const int KI = H_ / 32;   // 64

  #pragma unroll
  for (int j = 0; j < 2; j++) { g2l16(ga[j], AB + lao[j]); g2l16(gb[j], AB + lbo[j]); }

  for (int ki = 0; ki < KI; ki++) {
    int p = ki & 1;
    if (ki + 1 < KI) {
      int off = (ki + 1) * 32;
      unsigned short* nb = AB + (p ^ 1) * 8192;
      #pragma unroll
      for (int j = 0; j < 2; j++) {
        g2l16(ga[j] + off, nb + lao[j]);
        g2l16(gb[j] + off, nb + lbo[j]);
      }
      asm volatile("s_waitcnt vmcnt(4)" ::: "memory");
    } else {
      asm volatile("s_waitcnt vmcnt(0)" ::: "memory");
    }
    asm volatile("s_barrier" ::: "memory");

    const unsigned short* Ap = AB + p*8192;
    const unsigned short* Bp = Ap + 4096;
    int sl = (quad ^ r3) * 8;
    bf16x8 af[4], bfr[4];
    #pragma unroll
    for (int i = 0; i < 4; i++)
      af[i] = *(const bf16x8*)&Ap[(wm + i*16 + l16)*32 + sl];
    #pragma unroll
    for (int j = 0; j < 4; j++)
      bfr[j] = *(const bf16x8*)&Bp[(wn + j*16 + l16)*32 + sl];
    #pragma unroll
    for (int i = 0; i < 4; i++)
      #pragma unroll
      for (int j = 0; j < 4; j++)
        acc[i][j] = __builtin_amdgcn_mfma_f32_16x16x32_bf16(af[i], bfr[j], acc[i][j], 0, 0, 0);

    asm volatile("s_waitcnt lgkmcnt(0)" ::: "memory");
    asm volatile("s_barrier" ::: "memory");
  }

  // epilogue: per-wave LDS transpose -> coalesced bf16 16B stores
  unsigned short* Lt = AB + w*4096;
  #pragma unroll
  for (int j = 0; j < 4; j++) {
    int n = n0 + wn + j*16 + l16;
    float bias = b2[e * C_ + n];
    #pragma unroll
    for (int i = 0; i < 4; i++)
      #pragma unroll
      for (int r = 0; r < 4; r++)
        Lt[(i*16 + quad*4 + r)*64 + j*16 + l16] =
            (unsigned short)f2bf(acc[i][j][r] + bias);
  }
  #pragma unroll
  for (int it = 0; it < 8; it++) {
    int rloc = it*8 + (lane >> 3);
    int m = row0 + wm + rloc;
    uint4 vv = *(uint4*)&Lt[rloc*64 + (lane & 7)*8];
    if (m < rowEnd)
      *(uint4*)(Ys + (size_t)m * C_ + n0 + wn + (lane & 7)*8) = vv;
  }
}

// ---------------- combine: out[t] = g0*Ys[s0] + g1*Ys[s1] (bf16 Ys) ----------------
__global__ __launch_bounds__(256) void k_combine(
    const unsigned short* __restrict__ Ys, const int4* __restrict__ info,
    const int2* __restrict__ slots2, float* __restrict__ outp)
{
  int t = blockIdx.x * 4 + (threadIdx.x >> 6);
  int lane = threadIdx.x & 63;
  int4 nfo = info[t];
  int2 ss = slots2[t];
  float g0 = __int_as_float(nfo.z), g1 = __int_as_float(nfo.w);
  uint4 a = *(const uint4*)(Ys + (size_t)ss.x * C_ + lane*8);
  uint4 bb = *(const uint4*)(Ys + (size_t)ss.y * C_ + lane*8);
  unsigned int au[4] = {a.x, a.y, a.z, a.w};
  unsigned int bu[4] = {bb.x, bb.y, bb.z, bb.w};
  float vals[8];
  #pragma unroll
  for (int q = 0; q < 4; q++) {
    vals[q*2]   = g0*bf2f(au[q])       + g1*bf2f(bu[q]);
    vals[q*2+1] = g0*bf2f(au[q] >> 16) + g1*bf2f(bu[q] >> 16);
  }
  float4 o0, o1;
  o0.x = vals[0]; o0.y = vals[1]; o0.z = vals[2]; o0.w = vals[3];
  o1.x = vals[4]; o1.y = vals[5]; o1.z = vals[6]; o1.w = vals[7];
  float4* o = (float4*)(outp + (size_t)t * C_ + lane*8);
  o[0] = o0;
  o[1] = o1;
}

extern "C" void kernel_launch(void* const* d_in, const int* in_sizes, int n_in,
                              void* d_out, int out_size, void* d_ws, size_t ws_size,
                              hipStream_t stream)
{
  const float* x  = (const float*)d_in[0];
  const float* Wr = (const float*)d_in[1];
  const float* br = (const float*)d_in[2];
  const float* W1 = (const float*)d_in[3];
  const float* b1 = (const float*)d_in[4];
  const float* W2 = (const float*)d_in[5];
  const float* b2 = (const float*)d_in[6];
  float* out = (float*)d_out;   // [logits 65536 | idx 16384 | out 4194304]
  char* ws = (char*)d_ws;

  int*  counts = (int*)(ws + WS_COUNTS);
  int*  base   = (int*)(ws + WS_BASE);
  int*  offs   = (int*)(ws + WS_OFFS);
  int*  t1s    = (int*)(ws + WS_T1S);
  int4* info   = (int4*)(ws + WS_INFO);
  int*  tokl   = (int*)(ws + WS_TOKL);
  int2* slots2 = (int2*)(ws + WS_SLOTS);
  unsigned short* Xbf = (unsigned short*)(ws + WS_XBF);
  unsigned short* W1b = (unsigned short*)(ws + WS_W1B);
  unsigned short* W2b = (unsigned short*)(ws + WS_W2B);
  unsigned short* Hs  = (unsigned short*)(ws + WS_HS);
  unsigned short* Ys  = (unsigned short*)(ws + WS_YS);  // aliases Xbf+W1b

  hipMemsetAsync(counts, 0, NCH*8*sizeof(int), stream);

  k_transpose<<<dim3(H_/32, C_/128, E_), 256, 0, stream>>>(W1, W1b, C_, H_);
  k_transpose<<<dim3(C_/32, H_/128, E_), 256, 0, stream>>>(W2, W2b, H_, C_);
  k_router<<<NTOK/4, 256, 0, stream>>>(x, Wr, br, out, out + 65536, info, counts, Xbf);
  k_prefix<<<1, 256, 0, stream>>>(counts, base, offs, t1s);
  k_scatter<<<NCH, 64, 0, stream>>>(info, base, tokl, slots2);
  k_gemm1<<<17*128, 256, 0, stream>>>(Xbf, tokl, W1b, b1, Hs, offs, t1s);
  k_gemm2<<<17*32, 256, 0, stream>>>(Hs, W2b, b2, Ys, offs, t1s);
  k_combine<<<NTOK/4, 256, 0, stream>>>(Ys, info, slots2, out + 81920);
}